// Round 6
// baseline (1646.676 us; speedup 1.0000x reference)
//
#include <hip/hip_runtime.h>
#include <hip/hip_bf16.h>

// MyRnn: h_t = tanh(emb[idx_t] @ W_xh + b_h + h_{t-1} @ W_hh), 80 steps,
// out = sigmoid(h_80 @ W_out + b_out).
//
// R6: FRAGMENT-ORDER WEIGHT STREAM. R4/R5 identical counters proved the cost
// is the weight-stream access pattern (1KB-strided lanes -> 16 lines/load,
// 50% line use, ~6x below L2 ceiling), not register residency. Prep kernel
// now emits Wf[wave][kstep 0..19][nt][lane][8bf16]: each wave reads ONE
// contiguous 80KB slice per step (perfect coalescing, L2-resident 640KB).
// M=32 rows/block, 64 blocks x 512 thr (8 waves, 2/SIMD): halves per-XCD
// stream demand vs M=16/128blk. Stream 5.1 MB/step/XCD ~1.2us, MFMA 0.64us,
// LDS ~1.1us -> ~1.5us/step. Arch VGPRs ~90 (sB 48 + linear addrs) < 128 cap.
// h double-buffers through XOR-swizzled LDS; ONE __syncthreads per step.

#define T_LEN   80
#define EMB_D   100
#define UNITS   512
#define ROWS    32
#define NBLK    64               // 2048/32
#define NTHR    512
#define NW      8
#define NT      4                // 16-col n-tiles per wave (64 cols)
#define KSX     4                // x K-steps (128/32, zero-padded)
#define KSH     16               // hh K-steps (512/32)
#define KSALL   (KSX + KSH)      // 20 unified streamed ksteps
#define SDEPTH  3                // streamed pipeline depth
// Wf: per-wave slice = KSALL*NT*64 lanes*8 elems = 40960 bf16 (80 KB)
#define WSLICE  (KSALL * NT * 64 * 8)

typedef __bf16 bf16x8 __attribute__((ext_vector_type(8)));
typedef float  f32x4  __attribute__((ext_vector_type(4)));

__device__ __forceinline__ float fast_tanh(float x) {
    float e = __builtin_amdgcn_exp2f(x * 2.8853900817779268f);
    return 1.0f - 2.0f * __builtin_amdgcn_rcpf(1.0f + e);
}

// ---- prep: gather weights into MFMA-fragment order ----
// frag id f = ((wave*KSALL + i)*NT + nt)*64 + lane; elems Wf[f*8 .. f*8+7].
// i<KSX: W_xh kstep i (k = i*32 + q*8 + j, zero-pad k>=100); else W_hh
// kstep i-KSX. col = wave*64 + nt*16 + (lane&15), q = lane>>4.
__global__ void prep_kernel(const float* __restrict__ Whh,
                            const float* __restrict__ Wxh,
                            __bf16* __restrict__ Wf) {
    const int f    = blockIdx.x * 256 + threadIdx.x;   // 40960 frags
    const int lane = f & 63;
    const int t2   = f >> 6;
    const int nt   = t2 & (NT - 1);
    const int t3   = t2 >> 2;
    const int i    = t3 % KSALL;
    const int wave = t3 / KSALL;
    const int col  = (wave << 6) + (nt << 4) + (lane & 15);
    const int q    = lane >> 4;
    bf16x8 v;
    if (i < KSX) {
        const int k0 = (i << 5) + (q << 3);
        #pragma unroll
        for (int j = 0; j < 8; ++j)
            v[j] = (k0 + j < EMB_D) ? (__bf16)Wxh[(k0 + j) * UNITS + col]
                                    : (__bf16)0.0f;
    } else {
        const int k0 = ((i - KSX) << 5) + (q << 3);
        #pragma unroll
        for (int j = 0; j < 8; ++j)
            v[j] = (__bf16)Whh[(k0 + j) * UNITS + col];
    }
    *(bf16x8*)(Wf + (size_t)f * 8) = v;
}

__global__ __launch_bounds__(NTHR)
__attribute__((amdgpu_waves_per_eu(2, 2)))
void rnn_kernel(const int*   __restrict__ inputs,   // [2048][80]
                const float* __restrict__ emb,      // [35000][100]
                const float* __restrict__ bh,       // [512]
                const float* __restrict__ Wout,     // [512]
                const float* __restrict__ bout,     // [1]
                const __bf16* __restrict__ Wf,      // fragment-order (ws)
                float*       __restrict__ out)      // [2048]
{
    // h: 32 rows x 512 bf16; elem(r,k) = r*512 + (((k>>3)^(r&7))<<3) + (k&7)
    // x: 32 rows x 128 bf16; same swizzle, row stride 128.
    __shared__ alignas(16) __bf16 hbuf[2][ROWS * UNITS];  // 2 x 32 KB
    __shared__ alignas(16) __bf16 xbuf[2][ROWS * 128];    // 2 x 8 KB

    const int tid  = threadIdx.x;
    const int wave = tid >> 6;       // 0..7
    const int lane = tid & 63;
    const int q    = lane >> 4;
    const int ln   = lane & 15;
    const int e7   = ln & 7;
    const int qa   = q ^ (e7 & 3);
    const int kx   = e7 >> 2;
    const int r0   = blockIdx.x * ROWS;

    // linear per-wave fragment stream base (lane-contiguous)
    const __bf16* wbase = Wf + (size_t)wave * WSLICE + (lane << 3);
    // frag(i, nt) = wbase + ((i*NT + nt) << 9)   [512 elems per frag-group]

    float bhv[NT];
    #pragma unroll
    for (int nt = 0; nt < NT; ++nt)
        bhv[nt] = bh[(wave << 6) + (nt << 4) + ln];

    // zero LDS (h0 = 0; x pad cols stay 0)
    {
        int4 z; z.x = z.y = z.z = z.w = 0;
        int4* hp = (int4*)&hbuf[0][0];
        #pragma unroll
        for (int i = 0; i < 8; ++i) hp[tid + i * NTHR] = z;   // 64 KB
        int4* xp = (int4*)&xbuf[0][0];
        #pragma unroll
        for (int i = 0; i < 2; ++i) xp[tid + i * NTHR] = z;   // 16 KB
    }
    __syncthreads();

    // stage embedded x_t (bf16, swizzled); wave handles 4 rows
    auto stage = [&](int t, __bf16* xb) {
        #pragma unroll
        for (int rr = 0; rr < 4; ++rr) {
            const int r = (wave << 2) + rr;
            const int idxv = inputs[(r0 + r) * T_LEN + t];
            const float* er = emb + (size_t)idxv * EMB_D;
            const int k0 = lane;          // < 100 always
            xb[(r << 7) + ((((k0 >> 3) ^ (r & 7)) << 3) | (k0 & 7))] = (__bf16)er[k0];
            const int k1 = lane + 64;
            if (k1 < EMB_D)
                xb[(r << 7) + ((((k1 >> 3) ^ (r & 7)) << 3) | (k1 & 7))] = (__bf16)er[k1];
        }
    };

    auto step = [&](const __bf16* hb_r, const __bf16* xb_r, __bf16* hb_w) {
        // rotating streamed-B pipeline over the linear fragment walk
        bf16x8 sB[SDEPTH][NT];
        #pragma unroll
        for (int p = 0; p < SDEPTH; ++p)
            #pragma unroll
            for (int nt = 0; nt < NT; ++nt)
                sB[p][nt] = *(const bf16x8*)(wbase + (((p * NT + nt)) << 9));

        f32x4 acc[2][NT];
        #pragma unroll
        for (int mt = 0; mt < 2; ++mt)
            #pragma unroll
            for (int nt = 0; nt < NT; ++nt) {
                f32x4 a = {bhv[nt], bhv[nt], bhv[nt], bhv[nt]};
                acc[mt][nt] = a;
            }

        const int xb0 = (ln << 7) + (qa << 3);
        const int hb0 = (ln << 9) + (qa << 3);
        #pragma unroll
        for (int i = 0; i < KSALL; ++i) {
            const int s = i % SDEPTH;
            bf16x8 a0, a1;
            if (i < KSX) {
                a0 = *(const bf16x8*)&xb_r[xb0 + ((i ^ kx) << 5)];
                a1 = *(const bf16x8*)&xb_r[xb0 + (16 << 7) + ((i ^ kx) << 5)];
            } else {
                a0 = *(const bf16x8*)&hb_r[hb0 + (((i - KSX) ^ kx) << 5)];
                a1 = *(const bf16x8*)&hb_r[hb0 + (16 << 9) + (((i - KSX) ^ kx) << 5)];
            }
            #pragma unroll
            for (int nt = 0; nt < NT; ++nt)
                acc[0][nt] = __builtin_amdgcn_mfma_f32_16x16x32_bf16(a0, sB[s][nt], acc[0][nt], 0, 0, 0);
            #pragma unroll
            for (int nt = 0; nt < NT; ++nt)
                acc[1][nt] = __builtin_amdgcn_mfma_f32_16x16x32_bf16(a1, sB[s][nt], acc[1][nt], 0, 0, 0);
            if (i + SDEPTH < KSALL) {
                const int j = i + SDEPTH;
                #pragma unroll
                for (int nt = 0; nt < NT; ++nt)
                    sB[s][nt] = *(const bf16x8*)(wbase + ((j * NT + nt) << 9));
            }
        }
        // write h': C/D col=ln, row = mt*16 + 4q + i
        #pragma unroll
        for (int mt = 0; mt < 2; ++mt)
            #pragma unroll
            for (int nt = 0; nt < NT; ++nt) {
                const int cc = (wave << 3) + (nt << 1) + (ln >> 3);  // col>>3
                #pragma unroll
                for (int i = 0; i < 4; ++i) {
                    const int row = (mt << 4) + (q << 2) + i;
                    hb_w[(row << 9) + (((cc ^ (row & 7)) << 3) | (ln & 7))] =
                        (__bf16)fast_tanh(acc[mt][nt][i]);
                }
            }
    };

    stage(0, xbuf[0]);
    __syncthreads();

    #pragma unroll 1
    for (int t = 0; t < T_LEN; t += 2) {
        stage(t + 1, xbuf[1]);                        // t+1 <= 79
        step(hbuf[0], xbuf[0], hbuf[1]);
        __syncthreads();
        if (t + 2 < T_LEN) stage(t + 2, xbuf[0]);
        step(hbuf[1], xbuf[1], hbuf[0]);
        __syncthreads();
    }
    // h_last in hbuf[0], rows 0..31

    // output head: wave reduces 4 rows
    #pragma unroll
    for (int rr = 0; rr < 4; ++rr) {
        const int m = (wave << 2) + rr;
        const bf16x8 hv = *(const bf16x8*)&hbuf[0][(m << 9) + ((lane ^ (m & 7)) << 3)];
        float s = 0.0f;
        #pragma unroll
        for (int j = 0; j < 8; ++j)
            s += (float)hv[j] * Wout[(lane << 3) + j];
        #pragma unroll
        for (int off = 32; off > 0; off >>= 1)
            s += __shfl_down(s, off, 64);
        if (lane == 0) {
            const float logit = s + bout[0];
            out[r0 + m] = __builtin_amdgcn_rcpf(
                1.0f + __builtin_amdgcn_exp2f(-logit * 1.4426950408889634f));
        }
    }
}

extern "C" void kernel_launch(void* const* d_in, const int* in_sizes, int n_in,
                              void* d_out, int out_size, void* d_ws, size_t ws_size,
                              hipStream_t stream) {
    __bf16* Wf = (__bf16*)d_ws;                 // 8*40960*2 = 640 KB
    prep_kernel<<<dim3(160), dim3(256), 0, stream>>>(
        (const float*)d_in[3],   // W_hh
        (const float*)d_in[2],   // W_xh
        Wf);
    rnn_kernel<<<dim3(NBLK), dim3(NTHR), 0, stream>>>(
        (const int*)d_in[0],     // inputs
        (const float*)d_in[1],   // emb_table
        (const float*)d_in[4],   // b_h
        (const float*)d_in[5],   // W_out
        (const float*)d_in[6],   // b_out
        Wf,
        (float*)d_out);
}